// Round 8
// baseline (921.217 us; speedup 1.0000x reference)
//
#include <hip/hip_runtime.h>
#include <hip/hip_bf16.h>

#define NUM_USERS 100000
#define NUM_ITEMS 50000
#define N_NODES   150000
#define N_EDGES   4000000
#define H         64
#define BATCH     100000
#define MLP_HIDDEN 32
#define NBUCK     586          // ceil(N_NODES / 256); bucket = dst >> 8
#define BCAP      8192         // fixed bucket capacity (mean 6827, sigma 83)

typedef unsigned short ushort_t;

__device__ __forceinline__ float bf2f(ushort_t u) {
    return __uint_as_float(((unsigned)u) << 16);
}
__device__ __forceinline__ ushort_t f2bf(float f) {   // round-to-nearest-even
    unsigned u = __float_as_uint(f);
    u = u + 0x7FFFu + ((u >> 16) & 1u);
    return (ushort_t)(u >> 16);
}

// ---------------------------------------------------------------------------
// Init: x = concat(ue, ie) fp32  AND  xh = bf16(x).
__global__ __launch_bounds__(256) void init_kernel(const float* __restrict__ ue,
                                                   const float* __restrict__ ie,
                                                   float* __restrict__ x,
                                                   ushort_t* __restrict__ xh) {
    int i = blockIdx.x * 256 + threadIdx.x;        // float4 index, exact grid
    const int UN4 = NUM_USERS * H / 4;
    float4 v = (i < UN4) ? ((const float4*)ue)[i] : ((const float4*)ie)[i - UN4];
    ((float4*)x)[i] = v;
    uint2 p;
    p.x = (unsigned)f2bf(v.x) | ((unsigned)f2bf(v.y) << 16);
    p.y = (unsigned)f2bf(v.z) | ((unsigned)f2bf(v.w) << 16);
    ((uint2*)xh)[i] = p;
}

// ---------------------------------------------------------------------------
// CSR build pass 1: scatter edges into fixed-capacity buckets.
// Entry packed as (src << 8) | (dst & 255).
#define SCHUNK 8192
__global__ __launch_bounds__(256) void bucket_scatter_kernel(const int* __restrict__ src,
                                                             const int* __restrict__ dst,
                                                             int* __restrict__ bucketCnt,
                                                             int* __restrict__ ebuf) {
    __shared__ int histL[NBUCK];
    __shared__ int curL[NBUCK];
    int base = blockIdx.x * SCHUNK;
    int end = min(base + SCHUNK, N_EDGES);
    for (int i = threadIdx.x; i < NBUCK; i += 256) histL[i] = 0;
    __syncthreads();
    for (int e = base + threadIdx.x; e < end; e += 256)
        atomicAdd(&histL[dst[e] >> 8], 1);
    __syncthreads();
    for (int b = threadIdx.x; b < NBUCK; b += 256)
        curL[b] = histL[b] ? (b * BCAP + atomicAdd(&bucketCnt[b], histL[b])) : 0;
    __syncthreads();
    for (int e = base + threadIdx.x; e < end; e += 256) {
        int d = dst[e];
        int pos = atomicAdd(&curL[d >> 8], 1);
        ebuf[pos] = (src[e] << 8) | (d & 255);
    }
}

// CSR build pass 2: one block per bucket — local degrees, local scan, fill.
__global__ __launch_bounds__(256) void bucket_build_kernel(const int* __restrict__ ebuf,
                                                           const int* __restrict__ bucketCnt,
                                                           int* __restrict__ deg,
                                                           int* __restrict__ offsets,
                                                           int* __restrict__ csr) {
    __shared__ int degL[256];
    __shared__ int scanL[256];
    __shared__ int curL[256];
    int t = threadIdx.x;
    int b = blockIdx.x;
    int nodeBase = b << 8;
    int start = b * BCAP;
    int cnt = bucketCnt[b];

    degL[t] = 0;
    __syncthreads();
    for (int i = t; i < cnt; i += 256)
        atomicAdd(&degL[ebuf[start + i] & 255], 1);
    __syncthreads();

    int v = degL[t];
    scanL[t] = v;
    __syncthreads();
#pragma unroll
    for (int off = 1; off < 256; off <<= 1) {
        int u = (t >= off) ? scanL[t - off] : 0;
        __syncthreads();
        scanL[t] += u;
        __syncthreads();
    }
    int excl = scanL[t] - v;

    int node = nodeBase + t;
    if (node < N_NODES) {
        deg[node] = v;
        offsets[node] = start + excl;
    }
    curL[t] = excl;
    __syncthreads();

    for (int i = t; i < cnt; i += 256) {
        unsigned p = (unsigned)ebuf[start + i];
        int pos = atomicAdd(&curL[p & 255u], 1);
        csr[start + pos] = (int)(p >> 8);
    }
}

// ---------------------------------------------------------------------------
// Gather-mean over bf16 x: one wave per node, lane = feature. Writes bf16 mean.
__global__ __launch_bounds__(256, 8) void gather_mean_kernel(const ushort_t* __restrict__ xh,
                                                             ushort_t* __restrict__ mean_bf,
                                                             const int* __restrict__ offsets,
                                                             const int* __restrict__ deg,
                                                             const int* __restrict__ csr) {
    int slot = threadIdx.x >> 6;
    int h    = threadIdx.x & 63;
    int node = blockIdx.x * 4 + slot;              // N_NODES % 4 == 0

    int base = offsets[node];
    int cnt  = deg[node];

    float acc = 0.0f;
    for (int c = 0; c < cnt; c += 64) {
        int n = min(64, cnt - c);
        int sid = (c + h < cnt) ? csr[base + c + h] : 0;
        int i = 0;
        for (; i + 8 <= n; i += 8) {
            int s0 = __shfl(sid, i + 0, 64);
            int s1 = __shfl(sid, i + 1, 64);
            int s2 = __shfl(sid, i + 2, 64);
            int s3 = __shfl(sid, i + 3, 64);
            int s4 = __shfl(sid, i + 4, 64);
            int s5 = __shfl(sid, i + 5, 64);
            int s6 = __shfl(sid, i + 6, 64);
            int s7 = __shfl(sid, i + 7, 64);
            float v0 = bf2f(xh[s0 * H + h]);
            float v1 = bf2f(xh[s1 * H + h]);
            float v2 = bf2f(xh[s2 * H + h]);
            float v3 = bf2f(xh[s3 * H + h]);
            float v4 = bf2f(xh[s4 * H + h]);
            float v5 = bf2f(xh[s5 * H + h]);
            float v6 = bf2f(xh[s6 * H + h]);
            float v7 = bf2f(xh[s7 * H + h]);
            acc += ((v0 + v1) + (v2 + v3)) + ((v4 + v5) + (v6 + v7));
        }
        for (; i < n; ++i) {
            int s0 = __shfl(sid, i, 64);
            acc += bf2f(xh[s0 * H + h]);
        }
    }
    float mean = acc / fmaxf((float)cnt, 1.0f);
    mean_bf[node * H + h] = f2bf(mean);
}

// ---------------------------------------------------------------------------
// Transform: x = relu(mean @ Wl + bl + x @ Wr), IN PLACE; also emits bf16 x.
// 128 nodes/block, 256 threads; thread = 4 nodes x 8 features.
// mean/x streamed from GLOBAL; weights in 32 KB LDS.
// __launch_bounds__(256,4): cap at 128 VGPR — round 7 hit 256 VGPR / 10%
// occupancy and went latency-bound; one k-tile of operands live at a time.
__global__ __launch_bounds__(256, 4) void transform_kernel(float* __restrict__ x,
                                                           ushort_t* __restrict__ xh,
                                                           const ushort_t* __restrict__ mean_bf,
                                                           const float* __restrict__ Wl,
                                                           const float* __restrict__ bl,
                                                           const float* __restrict__ Wr,
                                                           int writeBf) {
    __shared__ float sWl[H * H];       // [k][h] 16 KB
    __shared__ float sWr[H * H];       // [k][h] 16 KB
    int t = threadIdx.x;
    for (int i = t; i < H * H / 4; i += 256) {
        ((float4*)sWl)[i] = ((const float4*)Wl)[i];
        ((float4*)sWr)[i] = ((const float4*)Wr)[i];
    }
    __syncthreads();

    int tx = t & 7;                    // feature octet: tx*8 .. tx*8+7
    int ty = t >> 3;                   // node quad
    int nbase = blockIdx.x * 128 + ty * 4;

    float acc[4][8];
#pragma unroll
    for (int j = 0; j < 4; ++j)
#pragma unroll
        for (int f = 0; f < 8; ++f) acc[j][f] = 0.0f;

    for (int kt = 0; kt < 16; ++kt) {  // k-tiles of 4 (NOT unrolled: keeps
        float m[4][4], xo[4][4];       // one tile of operands live -> low VGPR)
#pragma unroll
        for (int j = 0; j < 4; ++j) {
            int node = nbase + j;
            if (node < N_NODES) {
                uint2 mu = *(const uint2*)&mean_bf[node * H + kt * 4];
                m[j][0] = __uint_as_float(mu.x << 16);
                m[j][1] = __uint_as_float(mu.x & 0xFFFF0000u);
                m[j][2] = __uint_as_float(mu.y << 16);
                m[j][3] = __uint_as_float(mu.y & 0xFFFF0000u);
                float4 xv = *(const float4*)&x[node * H + kt * 4];
                xo[j][0] = xv.x; xo[j][1] = xv.y; xo[j][2] = xv.z; xo[j][3] = xv.w;
            } else {
#pragma unroll
                for (int q = 0; q < 4; ++q) { m[j][q] = 0.0f; xo[j][q] = 0.0f; }
            }
        }
#pragma unroll
        for (int kk = 0; kk < 4; ++kk) {
            int k = kt * 4 + kk;
            float4 wl0 = *(const float4*)&sWl[k * H + tx * 8];
            float4 wl1 = *(const float4*)&sWl[k * H + tx * 8 + 4];
            float4 wr0 = *(const float4*)&sWr[k * H + tx * 8];
            float4 wr1 = *(const float4*)&sWr[k * H + tx * 8 + 4];
#pragma unroll
            for (int j = 0; j < 4; ++j) {
                float mk = m[j][kk], xk = xo[j][kk];
                acc[j][0] = fmaf(mk, wl0.x, fmaf(xk, wr0.x, acc[j][0]));
                acc[j][1] = fmaf(mk, wl0.y, fmaf(xk, wr0.y, acc[j][1]));
                acc[j][2] = fmaf(mk, wl0.z, fmaf(xk, wr0.z, acc[j][2]));
                acc[j][3] = fmaf(mk, wl0.w, fmaf(xk, wr0.w, acc[j][3]));
                acc[j][4] = fmaf(mk, wl1.x, fmaf(xk, wr1.x, acc[j][4]));
                acc[j][5] = fmaf(mk, wl1.y, fmaf(xk, wr1.y, acc[j][5]));
                acc[j][6] = fmaf(mk, wl1.z, fmaf(xk, wr1.z, acc[j][6]));
                acc[j][7] = fmaf(mk, wl1.w, fmaf(xk, wr1.w, acc[j][7]));
            }
        }
    }

    float4 b0 = *(const float4*)&bl[tx * 8];
    float4 b1 = *(const float4*)&bl[tx * 8 + 4];
    const float bias[8] = {b0.x, b0.y, b0.z, b0.w, b1.x, b1.y, b1.z, b1.w};
#pragma unroll
    for (int j = 0; j < 4; ++j) {
        int node = nbase + j;
        if (node < N_NODES) {
            float o[8];
#pragma unroll
            for (int f = 0; f < 8; ++f) o[f] = fmaxf(acc[j][f] + bias[f], 0.0f);
            float4 s0 = make_float4(o[0], o[1], o[2], o[3]);
            float4 s1 = make_float4(o[4], o[5], o[6], o[7]);
            *(float4*)&x[node * H + tx * 8]     = s0;
            *(float4*)&x[node * H + tx * 8 + 4] = s1;
            if (writeBf) {
                uint4 p;
                p.x = (unsigned)f2bf(o[0]) | ((unsigned)f2bf(o[1]) << 16);
                p.y = (unsigned)f2bf(o[2]) | ((unsigned)f2bf(o[3]) << 16);
                p.z = (unsigned)f2bf(o[4]) | ((unsigned)f2bf(o[5]) << 16);
                p.w = (unsigned)f2bf(o[6]) | ((unsigned)f2bf(o[7]) << 16);
                *(uint4*)&xh[node * H + tx * 8] = p;
            }
        }
    }
}

// ---------------------------------------------------------------------------
// Final MLP: rating = clip(relu(pair @ W1 + b1) @ W2 + b2, 1, 5)
__global__ __launch_bounds__(256) void mlp_kernel(const float* __restrict__ x,
                                                  const int* __restrict__ uids,
                                                  const int* __restrict__ iids,
                                                  const float* __restrict__ W1,
                                                  const float* __restrict__ b1,
                                                  const float* __restrict__ W2,
                                                  const float* __restrict__ b2,
                                                  float* __restrict__ out) {
    __shared__ float sW1[2 * H * MLP_HIDDEN];
    __shared__ float sPair[8][2 * H];
    __shared__ float sW2[MLP_HIDDEN];

    for (int i = threadIdx.x; i < 2 * H * MLP_HIDDEN; i += 256) sW1[i] = W1[i];
    if (threadIdx.x < MLP_HIDDEN) sW2[threadIdx.x] = W2[threadIdx.x];

    int slot = threadIdx.x >> 5;
    int j    = threadIdx.x & 31;
    int b = blockIdx.x * 8 + slot;                 // BATCH % 8 == 0

    int u  = uids[b];
    int it = iids[b] + NUM_USERS;
    float2 a = *(const float2*)&x[u * H + j * 2];
    sPair[slot][j * 2]     = a.x;
    sPair[slot][j * 2 + 1] = a.y;
    float2 c = *(const float2*)&x[it * H + j * 2];
    sPair[slot][H + j * 2]     = c.x;
    sPair[slot][H + j * 2 + 1] = c.y;
    __syncthreads();

    float hacc = b1[j];
#pragma unroll
    for (int k = 0; k < 2 * H; ++k)
        hacc = fmaf(sPair[slot][k], sW1[k * MLP_HIDDEN + j], hacc);
    hacc = fmaxf(hacc, 0.0f);

    float r = hacc * sW2[j];
#pragma unroll
    for (int off = 16; off; off >>= 1) r += __shfl_down(r, off, 32);

    if (j == 0) out[b] = fminf(fmaxf(r + b2[0], 1.0f), 5.0f);
}

// ---------------------------------------------------------------------------
extern "C" void kernel_launch(void* const* d_in, const int* in_sizes, int n_in,
                              void* d_out, int out_size, void* d_ws, size_t ws_size,
                              hipStream_t stream) {
    const int*   edge_index = (const int*)d_in[0];
    const int*   user_ids   = (const int*)d_in[1];
    const int*   item_ids   = (const int*)d_in[2];
    const float* user_emb   = (const float*)d_in[3];
    const float* item_emb   = (const float*)d_in[4];
    const float* Wl         = (const float*)d_in[5];
    const float* bl         = (const float*)d_in[6];
    const float* Wr         = (const float*)d_in[7];
    const float* W1         = (const float*)d_in[8];
    const float* b1         = (const float*)d_in[9];
    const float* W2         = (const float*)d_in[10];
    const float* b2         = (const float*)d_in[11];
    float* out = (float*)d_out;

    const int* src = edge_index;
    const int* dst = edge_index + N_EDGES;

    const size_t NH = (size_t)N_NODES * H;
    float* x          = (float*)d_ws;                    // 38.4 MB fp32
    // ebuf region (19.2 MB) doubles as mean_bf after CSR build is done
    int* ebuf         = (int*)(x + NH);                  // NBUCK*BCAP*4 B
    ushort_t* mean_bf = (ushort_t*)ebuf;                 // 19.2 MB bf16 overlay
    ushort_t* xh      = (ushort_t*)(ebuf + (size_t)NBUCK * BCAP);  // 19.2 MB bf16
    int* deg          = (int*)(xh + NH);                 // 600 KB
    int* offsets      = deg + N_NODES;                   // 600 KB
    int* bucketCnt    = offsets + N_NODES;               // 2.3 KB
    int* csr          = bucketCnt + NBUCK;               // 19.2 MB (BCAP-strided)

    init_kernel<<<(N_NODES * H / 4) / 256, 256, 0, stream>>>(user_emb, item_emb, x, xh);

    // CSR build: fixed-capacity counting sort (graph identical across layers)
    hipMemsetAsync(bucketCnt, 0, NBUCK * sizeof(int), stream);
    bucket_scatter_kernel<<<(N_EDGES + SCHUNK - 1) / SCHUNK, 256, 0, stream>>>(
        src, dst, bucketCnt, ebuf);
    bucket_build_kernel<<<NBUCK, 256, 0, stream>>>(ebuf, bucketCnt, deg, offsets, csr);

    const int TGRID = (N_NODES + 127) / 128;             // 1172
    for (int l = 0; l < 3; ++l) {
        gather_mean_kernel<<<N_NODES / 4, 256, 0, stream>>>(xh, mean_bf, offsets, deg, csr);
        transform_kernel<<<TGRID, 256, 0, stream>>>(
            x, xh, mean_bf, Wl + (size_t)l * H * H, bl + (size_t)l * H,
            Wr + (size_t)l * H * H, l < 2 ? 1 : 0);
    }

    mlp_kernel<<<BATCH / 8, 256, 0, stream>>>(x, user_ids, item_ids, W1, b1, W2, b2, out);
}

// Round 9
// 569.474 us; speedup vs baseline: 1.6177x; 1.6177x over previous
//
#include <hip/hip_runtime.h>
#include <hip/hip_bf16.h>

#define NUM_USERS 100000
#define NUM_ITEMS 50000
#define N_NODES   150000
#define N_EDGES   4000000
#define H         64
#define BATCH     100000
#define MLP_HIDDEN 32
#define NBUCK     586          // ceil(N_NODES / 256); bucket = dst >> 8
#define BCAP      8192         // fixed bucket capacity (mean 6827, sigma 83)

typedef unsigned short ushort_t;

__device__ __forceinline__ float bf2f(ushort_t u) {
    return __uint_as_float(((unsigned)u) << 16);
}
__device__ __forceinline__ ushort_t f2bf(float f) {   // round-to-nearest-even
    unsigned u = __float_as_uint(f);
    u = u + 0x7FFFu + ((u >> 16) & 1u);
    return (ushort_t)(u >> 16);
}
__device__ __forceinline__ float bfLO(unsigned u) { return __uint_as_float(u << 16); }
__device__ __forceinline__ float bfHI(unsigned u) { return __uint_as_float(u & 0xFFFF0000u); }

// ---------------------------------------------------------------------------
// Init: x = concat(ue, ie) fp32  AND  xh = bf16(x).
__global__ __launch_bounds__(256) void init_kernel(const float* __restrict__ ue,
                                                   const float* __restrict__ ie,
                                                   float* __restrict__ x,
                                                   ushort_t* __restrict__ xh) {
    int i = blockIdx.x * 256 + threadIdx.x;        // float4 index, exact grid
    const int UN4 = NUM_USERS * H / 4;
    float4 v = (i < UN4) ? ((const float4*)ue)[i] : ((const float4*)ie)[i - UN4];
    ((float4*)x)[i] = v;
    uint2 p;
    p.x = (unsigned)f2bf(v.x) | ((unsigned)f2bf(v.y) << 16);
    p.y = (unsigned)f2bf(v.z) | ((unsigned)f2bf(v.w) << 16);
    ((uint2*)xh)[i] = p;
}

// ---------------------------------------------------------------------------
// CSR build pass 1: scatter edges into fixed-capacity buckets.
// Entry packed as (src << 8) | (dst & 255).
#define SCHUNK 8192
__global__ __launch_bounds__(256) void bucket_scatter_kernel(const int* __restrict__ src,
                                                             const int* __restrict__ dst,
                                                             int* __restrict__ bucketCnt,
                                                             int* __restrict__ ebuf) {
    __shared__ int histL[NBUCK];
    __shared__ int curL[NBUCK];
    int base = blockIdx.x * SCHUNK;
    int end = min(base + SCHUNK, N_EDGES);
    for (int i = threadIdx.x; i < NBUCK; i += 256) histL[i] = 0;
    __syncthreads();
    for (int e = base + threadIdx.x; e < end; e += 256)
        atomicAdd(&histL[dst[e] >> 8], 1);
    __syncthreads();
    for (int b = threadIdx.x; b < NBUCK; b += 256)
        curL[b] = histL[b] ? (b * BCAP + atomicAdd(&bucketCnt[b], histL[b])) : 0;
    __syncthreads();
    for (int e = base + threadIdx.x; e < end; e += 256) {
        int d = dst[e];
        int pos = atomicAdd(&curL[d >> 8], 1);
        ebuf[pos] = (src[e] << 8) | (d & 255);
    }
}

// CSR build pass 2: one block per bucket — local degrees, local scan, fill.
__global__ __launch_bounds__(256) void bucket_build_kernel(const int* __restrict__ ebuf,
                                                           const int* __restrict__ bucketCnt,
                                                           int* __restrict__ deg,
                                                           int* __restrict__ offsets,
                                                           int* __restrict__ csr) {
    __shared__ int degL[256];
    __shared__ int scanL[256];
    __shared__ int curL[256];
    int t = threadIdx.x;
    int b = blockIdx.x;
    int nodeBase = b << 8;
    int start = b * BCAP;
    int cnt = bucketCnt[b];

    degL[t] = 0;
    __syncthreads();
    for (int i = t; i < cnt; i += 256)
        atomicAdd(&degL[ebuf[start + i] & 255], 1);
    __syncthreads();

    int v = degL[t];
    scanL[t] = v;
    __syncthreads();
#pragma unroll
    for (int off = 1; off < 256; off <<= 1) {
        int u = (t >= off) ? scanL[t - off] : 0;
        __syncthreads();
        scanL[t] += u;
        __syncthreads();
    }
    int excl = scanL[t] - v;

    int node = nodeBase + t;
    if (node < N_NODES) {
        deg[node] = v;
        offsets[node] = start + excl;
    }
    curL[t] = excl;
    __syncthreads();

    for (int i = t; i < cnt; i += 256) {
        unsigned p = (unsigned)ebuf[start + i];
        int pos = atomicAdd(&curL[p & 255u], 1);
        csr[start + pos] = (int)(p >> 8);
    }
}

// ---------------------------------------------------------------------------
// Gather-mean over bf16 x: one wave per node, lane = feature. Writes bf16 mean.
__global__ __launch_bounds__(256, 8) void gather_mean_kernel(const ushort_t* __restrict__ xh,
                                                             ushort_t* __restrict__ mean_bf,
                                                             const int* __restrict__ offsets,
                                                             const int* __restrict__ deg,
                                                             const int* __restrict__ csr) {
    int slot = threadIdx.x >> 6;
    int h    = threadIdx.x & 63;
    int node = blockIdx.x * 4 + slot;              // N_NODES % 4 == 0

    int base = offsets[node];
    int cnt  = deg[node];

    float acc = 0.0f;
    for (int c = 0; c < cnt; c += 64) {
        int n = min(64, cnt - c);
        int sid = (c + h < cnt) ? csr[base + c + h] : 0;
        int i = 0;
        for (; i + 8 <= n; i += 8) {
            int s0 = __shfl(sid, i + 0, 64);
            int s1 = __shfl(sid, i + 1, 64);
            int s2 = __shfl(sid, i + 2, 64);
            int s3 = __shfl(sid, i + 3, 64);
            int s4 = __shfl(sid, i + 4, 64);
            int s5 = __shfl(sid, i + 5, 64);
            int s6 = __shfl(sid, i + 6, 64);
            int s7 = __shfl(sid, i + 7, 64);
            float v0 = bf2f(xh[s0 * H + h]);
            float v1 = bf2f(xh[s1 * H + h]);
            float v2 = bf2f(xh[s2 * H + h]);
            float v3 = bf2f(xh[s3 * H + h]);
            float v4 = bf2f(xh[s4 * H + h]);
            float v5 = bf2f(xh[s5 * H + h]);
            float v6 = bf2f(xh[s6 * H + h]);
            float v7 = bf2f(xh[s7 * H + h]);
            acc += ((v0 + v1) + (v2 + v3)) + ((v4 + v5) + (v6 + v7));
        }
        for (; i < n; ++i) {
            int s0 = __shfl(sid, i, 64);
            acc += bf2f(xh[s0 * H + h]);
        }
    }
    float mean = acc / fmaxf((float)cnt, 1.0f);
    mean_bf[node * H + h] = f2bf(mean);
}

// ---------------------------------------------------------------------------
// Transform: x = relu(mean @ Wl + bl + x @ Wr), IN PLACE; also emits bf16 x.
// 128 nodes/block, 256 threads; thread = 4 nodes x 8 features.
// mean/x staged in LDS as bf16 k-PAIRS transposed: sMT[kp][node] holds
// {k=2kp, k=2kp+1} packed in one uint -> one ds_read_b128 = 4 nodes x 2 k.
// Weights f32 in LDS. All operands LDS-resident -> short live ranges, no
// launch_bounds cap (rounds 7/8 showed global-streamed operands blow regalloc).
__global__ __launch_bounds__(256) void transform_kernel(float* __restrict__ x,
                                                        ushort_t* __restrict__ xh,
                                                        const ushort_t* __restrict__ mean_bf,
                                                        const float* __restrict__ Wl,
                                                        const float* __restrict__ bl,
                                                        const float* __restrict__ Wr,
                                                        int writeBf) {
    __shared__ float    sWl[H * H];        // [k][h] 16 KB
    __shared__ float    sWr[H * H];        // [k][h] 16 KB
    __shared__ unsigned sMT[H / 2][128];   // [kpair][node] bf16x2, 16 KB
    __shared__ unsigned sXT[H / 2][128];   // [kpair][node] bf16x2, 16 KB

    int t = threadIdx.x;
    int node0 = blockIdx.x * 128;

    for (int i = t; i < H * H / 4; i += 256) {
        ((float4*)sWl)[i] = ((const float4*)Wl)[i];
        ((float4*)sWr)[i] = ((const float4*)Wr)[i];
    }
    // Stage mean/x transposed: idx -> (quad q, node n); consecutive lanes ->
    // consecutive n -> conflict-free b32 writes.
#pragma unroll
    for (int it = 0; it < 8; ++it) {
        int idx = it * 256 + t;
        int n = idx & 127;
        int q = idx >> 7;                  // float4-quad 0..15 (k = 4q..4q+3)
        int node = node0 + n;
        uint2 mu = make_uint2(0u, 0u);
        uint2 xu = make_uint2(0u, 0u);
        if (node < N_NODES) {
            mu = *(const uint2*)&mean_bf[node * H + q * 4];   // 4 bf16, k-major
            float4 xv = *(const float4*)&x[node * H + q * 4];
            xu.x = (unsigned)f2bf(xv.x) | ((unsigned)f2bf(xv.y) << 16);
            xu.y = (unsigned)f2bf(xv.z) | ((unsigned)f2bf(xv.w) << 16);
        }
        sMT[q * 2][n]     = mu.x;
        sMT[q * 2 + 1][n] = mu.y;
        sXT[q * 2][n]     = xu.x;
        sXT[q * 2 + 1][n] = xu.y;
    }
    __syncthreads();

    int tx = t & 7;                        // feature octet: tx*8 .. tx*8+7
    int ty = t >> 3;                       // node quad 0..31
    int nbase = node0 + ty * 4;

    float acc[4][8];
#pragma unroll
    for (int j = 0; j < 4; ++j)
#pragma unroll
        for (int f = 0; f < 8; ++f) acc[j][f] = 0.0f;

    for (int kp = 0; kp < H / 2; ++kp) {   // k-pairs
        uint4 mu = *(const uint4*)&sMT[kp][ty * 4];   // 4 nodes x {k0,k1}
        uint4 xu = *(const uint4*)&sXT[kp][ty * 4];
        int k0 = kp * 2;
        float4 wl00 = *(const float4*)&sWl[k0 * H + tx * 8];
        float4 wl01 = *(const float4*)&sWl[k0 * H + tx * 8 + 4];
        float4 wr00 = *(const float4*)&sWr[k0 * H + tx * 8];
        float4 wr01 = *(const float4*)&sWr[k0 * H + tx * 8 + 4];
        float4 wl10 = *(const float4*)&sWl[(k0 + 1) * H + tx * 8];
        float4 wl11 = *(const float4*)&sWl[(k0 + 1) * H + tx * 8 + 4];
        float4 wr10 = *(const float4*)&sWr[(k0 + 1) * H + tx * 8];
        float4 wr11 = *(const float4*)&sWr[(k0 + 1) * H + tx * 8 + 4];
        const float wl0[8] = {wl00.x, wl00.y, wl00.z, wl00.w, wl01.x, wl01.y, wl01.z, wl01.w};
        const float wr0[8] = {wr00.x, wr00.y, wr00.z, wr00.w, wr01.x, wr01.y, wr01.z, wr01.w};
        const float wl1[8] = {wl10.x, wl10.y, wl10.z, wl10.w, wl11.x, wl11.y, wl11.z, wl11.w};
        const float wr1[8] = {wr10.x, wr10.y, wr10.z, wr10.w, wr11.x, wr11.y, wr11.z, wr11.w};
        const unsigned mua[4] = {mu.x, mu.y, mu.z, mu.w};
        const unsigned xua[4] = {xu.x, xu.y, xu.z, xu.w};
#pragma unroll
        for (int j = 0; j < 4; ++j) {
            float m0 = bfLO(mua[j]), m1 = bfHI(mua[j]);
            float x0 = bfLO(xua[j]), x1 = bfHI(xua[j]);
#pragma unroll
            for (int f = 0; f < 8; ++f) {
                float a = acc[j][f];
                a = fmaf(m0, wl0[f], a);
                a = fmaf(x0, wr0[f], a);
                a = fmaf(m1, wl1[f], a);
                a = fmaf(x1, wr1[f], a);
                acc[j][f] = a;
            }
        }
    }

    float4 b0 = *(const float4*)&bl[tx * 8];
    float4 b1 = *(const float4*)&bl[tx * 8 + 4];
    const float bias[8] = {b0.x, b0.y, b0.z, b0.w, b1.x, b1.y, b1.z, b1.w};
#pragma unroll
    for (int j = 0; j < 4; ++j) {
        int node = nbase + j;
        if (node < N_NODES) {
            float o[8];
#pragma unroll
            for (int f = 0; f < 8; ++f) o[f] = fmaxf(acc[j][f] + bias[f], 0.0f);
            *(float4*)&x[node * H + tx * 8]     = make_float4(o[0], o[1], o[2], o[3]);
            *(float4*)&x[node * H + tx * 8 + 4] = make_float4(o[4], o[5], o[6], o[7]);
            if (writeBf) {
                uint4 p;
                p.x = (unsigned)f2bf(o[0]) | ((unsigned)f2bf(o[1]) << 16);
                p.y = (unsigned)f2bf(o[2]) | ((unsigned)f2bf(o[3]) << 16);
                p.z = (unsigned)f2bf(o[4]) | ((unsigned)f2bf(o[5]) << 16);
                p.w = (unsigned)f2bf(o[6]) | ((unsigned)f2bf(o[7]) << 16);
                *(uint4*)&xh[node * H + tx * 8] = p;
            }
        }
    }
}

// ---------------------------------------------------------------------------
// Final MLP: rating = clip(relu(pair @ W1 + b1) @ W2 + b2, 1, 5)
__global__ __launch_bounds__(256) void mlp_kernel(const float* __restrict__ x,
                                                  const int* __restrict__ uids,
                                                  const int* __restrict__ iids,
                                                  const float* __restrict__ W1,
                                                  const float* __restrict__ b1,
                                                  const float* __restrict__ W2,
                                                  const float* __restrict__ b2,
                                                  float* __restrict__ out) {
    __shared__ float sW1[2 * H * MLP_HIDDEN];
    __shared__ float sPair[8][2 * H];
    __shared__ float sW2[MLP_HIDDEN];

    for (int i = threadIdx.x; i < 2 * H * MLP_HIDDEN; i += 256) sW1[i] = W1[i];
    if (threadIdx.x < MLP_HIDDEN) sW2[threadIdx.x] = W2[threadIdx.x];

    int slot = threadIdx.x >> 5;
    int j    = threadIdx.x & 31;
    int b = blockIdx.x * 8 + slot;                 // BATCH % 8 == 0

    int u  = uids[b];
    int it = iids[b] + NUM_USERS;
    float2 a = *(const float2*)&x[u * H + j * 2];
    sPair[slot][j * 2]     = a.x;
    sPair[slot][j * 2 + 1] = a.y;
    float2 c = *(const float2*)&x[it * H + j * 2];
    sPair[slot][H + j * 2]     = c.x;
    sPair[slot][H + j * 2 + 1] = c.y;
    __syncthreads();

    float hacc = b1[j];
#pragma unroll
    for (int k = 0; k < 2 * H; ++k)
        hacc = fmaf(sPair[slot][k], sW1[k * MLP_HIDDEN + j], hacc);
    hacc = fmaxf(hacc, 0.0f);

    float r = hacc * sW2[j];
#pragma unroll
    for (int off = 16; off; off >>= 1) r += __shfl_down(r, off, 32);

    if (j == 0) out[b] = fminf(fmaxf(r + b2[0], 1.0f), 5.0f);
}

// ---------------------------------------------------------------------------
extern "C" void kernel_launch(void* const* d_in, const int* in_sizes, int n_in,
                              void* d_out, int out_size, void* d_ws, size_t ws_size,
                              hipStream_t stream) {
    const int*   edge_index = (const int*)d_in[0];
    const int*   user_ids   = (const int*)d_in[1];
    const int*   item_ids   = (const int*)d_in[2];
    const float* user_emb   = (const float*)d_in[3];
    const float* item_emb   = (const float*)d_in[4];
    const float* Wl         = (const float*)d_in[5];
    const float* bl         = (const float*)d_in[6];
    const float* Wr         = (const float*)d_in[7];
    const float* W1         = (const float*)d_in[8];
    const float* b1         = (const float*)d_in[9];
    const float* W2         = (const float*)d_in[10];
    const float* b2         = (const float*)d_in[11];
    float* out = (float*)d_out;

    const int* src = edge_index;
    const int* dst = edge_index + N_EDGES;

    const size_t NH = (size_t)N_NODES * H;
    float* x          = (float*)d_ws;                    // 38.4 MB fp32
    // ebuf region (19.2 MB) doubles as mean_bf after CSR build is done
    int* ebuf         = (int*)(x + NH);                  // NBUCK*BCAP*4 B
    ushort_t* mean_bf = (ushort_t*)ebuf;                 // 19.2 MB bf16 overlay
    ushort_t* xh      = (ushort_t*)(ebuf + (size_t)NBUCK * BCAP);  // 19.2 MB bf16
    int* deg          = (int*)(xh + NH);                 // 600 KB
    int* offsets      = deg + N_NODES;                   // 600 KB
    int* bucketCnt    = offsets + N_NODES;               // 2.3 KB
    int* csr          = bucketCnt + NBUCK;               // 19.2 MB (BCAP-strided)

    init_kernel<<<(N_NODES * H / 4) / 256, 256, 0, stream>>>(user_emb, item_emb, x, xh);

    // CSR build: fixed-capacity counting sort (graph identical across layers)
    hipMemsetAsync(bucketCnt, 0, NBUCK * sizeof(int), stream);
    bucket_scatter_kernel<<<(N_EDGES + SCHUNK - 1) / SCHUNK, 256, 0, stream>>>(
        src, dst, bucketCnt, ebuf);
    bucket_build_kernel<<<NBUCK, 256, 0, stream>>>(ebuf, bucketCnt, deg, offsets, csr);

    const int TGRID = (N_NODES + 127) / 128;             // 1172
    for (int l = 0; l < 3; ++l) {
        gather_mean_kernel<<<N_NODES / 4, 256, 0, stream>>>(xh, mean_bf, offsets, deg, csr);
        transform_kernel<<<TGRID, 256, 0, stream>>>(
            x, xh, mean_bf, Wl + (size_t)l * H * H, bl + (size_t)l * H,
            Wr + (size_t)l * H * H, l < 2 ? 1 : 0);
    }

    mlp_kernel<<<BATCH / 8, 256, 0, stream>>>(x, user_ids, item_ids, W1, b1, W2, b2, out);
}

// Round 10
// 517.995 us; speedup vs baseline: 1.7784x; 1.0994x over previous
//
#include <hip/hip_runtime.h>
#include <hip/hip_bf16.h>

#define NUM_USERS 100000
#define NUM_ITEMS 50000
#define N_NODES   150000
#define N_EDGES   4000000
#define H         64
#define BATCH     100000
#define MLP_HIDDEN 32
#define NBUCK     586          // ceil(N_NODES / 256); bucket = dst >> 8
#define BCAP      8192         // fixed bucket capacity (mean 6827, sigma 83)

typedef unsigned short ushort_t;

__device__ __forceinline__ float bf2f(ushort_t u) {
    return __uint_as_float(((unsigned)u) << 16);
}
__device__ __forceinline__ ushort_t f2bf(float f) {   // round-to-nearest-even
    unsigned u = __float_as_uint(f);
    u = u + 0x7FFFu + ((u >> 16) & 1u);
    return (ushort_t)(u >> 16);
}
__device__ __forceinline__ float bfLO(unsigned u) { return __uint_as_float(u << 16); }
__device__ __forceinline__ float bfHI(unsigned u) { return __uint_as_float(u & 0xFFFF0000u); }

// ---------------------------------------------------------------------------
// Init: x = concat(ue, ie) fp32  AND  xh = bf16(x).
__global__ __launch_bounds__(256) void init_kernel(const float* __restrict__ ue,
                                                   const float* __restrict__ ie,
                                                   float* __restrict__ x,
                                                   ushort_t* __restrict__ xh) {
    int i = blockIdx.x * 256 + threadIdx.x;        // float4 index, exact grid
    const int UN4 = NUM_USERS * H / 4;
    float4 v = (i < UN4) ? ((const float4*)ue)[i] : ((const float4*)ie)[i - UN4];
    ((float4*)x)[i] = v;
    uint2 p;
    p.x = (unsigned)f2bf(v.x) | ((unsigned)f2bf(v.y) << 16);
    p.y = (unsigned)f2bf(v.z) | ((unsigned)f2bf(v.w) << 16);
    ((uint2*)xh)[i] = p;
}

// ---------------------------------------------------------------------------
// CSR build pass 1: scatter edges into fixed-capacity buckets.
// Entry packed as (src << 8) | (dst & 255).
#define SCHUNK 8192
__global__ __launch_bounds__(256) void bucket_scatter_kernel(const int* __restrict__ src,
                                                             const int* __restrict__ dst,
                                                             int* __restrict__ bucketCnt,
                                                             int* __restrict__ ebuf) {
    __shared__ int histL[NBUCK];
    __shared__ int curL[NBUCK];
    int base = blockIdx.x * SCHUNK;
    int end = min(base + SCHUNK, N_EDGES);
    for (int i = threadIdx.x; i < NBUCK; i += 256) histL[i] = 0;
    __syncthreads();
    for (int e = base + threadIdx.x; e < end; e += 256)
        atomicAdd(&histL[dst[e] >> 8], 1);
    __syncthreads();
    for (int b = threadIdx.x; b < NBUCK; b += 256)
        curL[b] = histL[b] ? (b * BCAP + atomicAdd(&bucketCnt[b], histL[b])) : 0;
    __syncthreads();
    for (int e = base + threadIdx.x; e < end; e += 256) {
        int d = dst[e];
        int pos = atomicAdd(&curL[d >> 8], 1);
        ebuf[pos] = (src[e] << 8) | (d & 255);
    }
}

// CSR build pass 2: one block per bucket — local degrees, local scan, fill.
__global__ __launch_bounds__(256) void bucket_build_kernel(const int* __restrict__ ebuf,
                                                           const int* __restrict__ bucketCnt,
                                                           int* __restrict__ deg,
                                                           int* __restrict__ offsets,
                                                           int* __restrict__ csr) {
    __shared__ int degL[256];
    __shared__ int scanL[256];
    __shared__ int curL[256];
    int t = threadIdx.x;
    int b = blockIdx.x;
    int nodeBase = b << 8;
    int start = b * BCAP;
    int cnt = bucketCnt[b];

    degL[t] = 0;
    __syncthreads();
    for (int i = t; i < cnt; i += 256)
        atomicAdd(&degL[ebuf[start + i] & 255], 1);
    __syncthreads();

    int v = degL[t];
    scanL[t] = v;
    __syncthreads();
#pragma unroll
    for (int off = 1; off < 256; off <<= 1) {
        int u = (t >= off) ? scanL[t - off] : 0;
        __syncthreads();
        scanL[t] += u;
        __syncthreads();
    }
    int excl = scanL[t] - v;

    int node = nodeBase + t;
    if (node < N_NODES) {
        deg[node] = v;
        offsets[node] = start + excl;
    }
    curL[t] = excl;
    __syncthreads();

    for (int i = t; i < cnt; i += 256) {
        unsigned p = (unsigned)ebuf[start + i];
        int pos = atomicAdd(&curL[p & 255u], 1);
        csr[start + pos] = (int)(p >> 8);
    }
}

// ---------------------------------------------------------------------------
// Gather-mean over bf16 x: one wave per node, 4 EDGES PER WAVE-INSTRUCTION.
// Lane layout: q = lane>>4 selects edge within quad, fp = lane&15 selects the
// feature quad (4 bf16 = one uint2 load). Round 9 was VALU-issue-bound
// (~16 instr/edge at 2-B loads); this is ~4 instr/edge at 8-B loads.
__global__ __launch_bounds__(256, 8) void gather_mean_kernel(const ushort_t* __restrict__ xh,
                                                             ushort_t* __restrict__ mean_bf,
                                                             const int* __restrict__ offsets,
                                                             const int* __restrict__ deg,
                                                             const int* __restrict__ csr) {
    int slot = threadIdx.x >> 6;
    int lane = threadIdx.x & 63;
    int q    = lane >> 4;              // edge-in-quad 0..3
    int fp   = lane & 15;              // feature-quad 0..15
    int node = blockIdx.x * 4 + slot;  // N_NODES % 4 == 0

    int base = offsets[node];
    int cnt  = deg[node];
    const uint2* xr = (const uint2*)xh;        // rows of 16 uint2 (64 bf16)

    float a0 = 0.f, a1 = 0.f, a2 = 0.f, a3 = 0.f;

    for (int c = 0; c < cnt; c += 64) {
        int n = min(64, cnt - c);
        int sid = (c + lane < cnt) ? csr[base + c + lane] : 0;
        int nquad = (n + 3) >> 2;
#define PROC(JJ) { int e = 4 * (JJ) + q;                                  \
        int s = __shfl(sid, e, 64);                                       \
        uint2 u = xr[s * 16 + fp];                                        \
        if (c + e >= cnt) { u.x = 0u; u.y = 0u; }                         \
        a0 += bfLO(u.x); a1 += bfHI(u.x); a2 += bfLO(u.y); a3 += bfHI(u.y); }
        int j = 0;
        for (; j + 2 <= nquad; j += 2) { PROC(j) PROC(j + 1) }
        for (; j < nquad; ++j) { PROC(j) }
#undef PROC
    }

    // fold the 4 edge-quad copies: xor-16 then xor-32
    a0 += __shfl_xor(a0, 16, 64); a1 += __shfl_xor(a1, 16, 64);
    a2 += __shfl_xor(a2, 16, 64); a3 += __shfl_xor(a3, 16, 64);
    a0 += __shfl_xor(a0, 32, 64); a1 += __shfl_xor(a1, 32, 64);
    a2 += __shfl_xor(a2, 32, 64); a3 += __shfl_xor(a3, 32, 64);

    if (lane < 16) {
        float rc = 1.0f / fmaxf((float)cnt, 1.0f);
        uint2 p;
        p.x = (unsigned)f2bf(a0 * rc) | ((unsigned)f2bf(a1 * rc) << 16);
        p.y = (unsigned)f2bf(a2 * rc) | ((unsigned)f2bf(a3 * rc) << 16);
        *(uint2*)&mean_bf[node * H + fp * 4] = p;
    }
}

// ---------------------------------------------------------------------------
// Transform: x = relu(mean @ Wl + bl + x @ Wr), IN PLACE; also emits bf16 x.
// 128 nodes/block, 256 threads; thread = 4 nodes x 8 features.
// mean/x staged in LDS as bf16 k-PAIRS transposed: sMT[kp][node] holds
// {k=2kp, k=2kp+1} packed in one uint -> one ds_read_b128 = 4 nodes x 2 k.
// Weights f32 in LDS. All operands LDS-resident -> short live ranges.
__global__ __launch_bounds__(256) void transform_kernel(float* __restrict__ x,
                                                        ushort_t* __restrict__ xh,
                                                        const ushort_t* __restrict__ mean_bf,
                                                        const float* __restrict__ Wl,
                                                        const float* __restrict__ bl,
                                                        const float* __restrict__ Wr,
                                                        int writeBf) {
    __shared__ float    sWl[H * H];        // [k][h] 16 KB
    __shared__ float    sWr[H * H];        // [k][h] 16 KB
    __shared__ unsigned sMT[H / 2][128];   // [kpair][node] bf16x2, 16 KB
    __shared__ unsigned sXT[H / 2][128];   // [kpair][node] bf16x2, 16 KB

    int t = threadIdx.x;
    int node0 = blockIdx.x * 128;

    for (int i = t; i < H * H / 4; i += 256) {
        ((float4*)sWl)[i] = ((const float4*)Wl)[i];
        ((float4*)sWr)[i] = ((const float4*)Wr)[i];
    }
#pragma unroll
    for (int it = 0; it < 8; ++it) {
        int idx = it * 256 + t;
        int n = idx & 127;
        int qd = idx >> 7;                 // float4-quad 0..15 (k = 4q..4q+3)
        int node = node0 + n;
        uint2 mu = make_uint2(0u, 0u);
        uint2 xu = make_uint2(0u, 0u);
        if (node < N_NODES) {
            mu = *(const uint2*)&mean_bf[node * H + qd * 4];
            float4 xv = *(const float4*)&x[node * H + qd * 4];
            xu.x = (unsigned)f2bf(xv.x) | ((unsigned)f2bf(xv.y) << 16);
            xu.y = (unsigned)f2bf(xv.z) | ((unsigned)f2bf(xv.w) << 16);
        }
        sMT[qd * 2][n]     = mu.x;
        sMT[qd * 2 + 1][n] = mu.y;
        sXT[qd * 2][n]     = xu.x;
        sXT[qd * 2 + 1][n] = xu.y;
    }
    __syncthreads();

    int tx = t & 7;                        // feature octet: tx*8 .. tx*8+7
    int ty = t >> 3;                       // node quad 0..31
    int nbase = node0 + ty * 4;

    float acc[4][8];
#pragma unroll
    for (int j = 0; j < 4; ++j)
#pragma unroll
        for (int f = 0; f < 8; ++f) acc[j][f] = 0.0f;

    for (int kp = 0; kp < H / 2; ++kp) {   // k-pairs
        uint4 mu = *(const uint4*)&sMT[kp][ty * 4];   // 4 nodes x {k0,k1}
        uint4 xu = *(const uint4*)&sXT[kp][ty * 4];
        int k0 = kp * 2;
        float4 wl00 = *(const float4*)&sWl[k0 * H + tx * 8];
        float4 wl01 = *(const float4*)&sWl[k0 * H + tx * 8 + 4];
        float4 wr00 = *(const float4*)&sWr[k0 * H + tx * 8];
        float4 wr01 = *(const float4*)&sWr[k0 * H + tx * 8 + 4];
        float4 wl10 = *(const float4*)&sWl[(k0 + 1) * H + tx * 8];
        float4 wl11 = *(const float4*)&sWl[(k0 + 1) * H + tx * 8 + 4];
        float4 wr10 = *(const float4*)&sWr[(k0 + 1) * H + tx * 8];
        float4 wr11 = *(const float4*)&sWr[(k0 + 1) * H + tx * 8 + 4];
        const float wl0[8] = {wl00.x, wl00.y, wl00.z, wl00.w, wl01.x, wl01.y, wl01.z, wl01.w};
        const float wr0[8] = {wr00.x, wr00.y, wr00.z, wr00.w, wr01.x, wr01.y, wr01.z, wr01.w};
        const float wl1[8] = {wl10.x, wl10.y, wl10.z, wl10.w, wl11.x, wl11.y, wl11.z, wl11.w};
        const float wr1[8] = {wr10.x, wr10.y, wr10.z, wr10.w, wr11.x, wr11.y, wr11.z, wr11.w};
        const unsigned mua[4] = {mu.x, mu.y, mu.z, mu.w};
        const unsigned xua[4] = {xu.x, xu.y, xu.z, xu.w};
#pragma unroll
        for (int j = 0; j < 4; ++j) {
            float m0 = bfLO(mua[j]), m1 = bfHI(mua[j]);
            float x0 = bfLO(xua[j]), x1 = bfHI(xua[j]);
#pragma unroll
            for (int f = 0; f < 8; ++f) {
                float a = acc[j][f];
                a = fmaf(m0, wl0[f], a);
                a = fmaf(x0, wr0[f], a);
                a = fmaf(m1, wl1[f], a);
                a = fmaf(x1, wr1[f], a);
                acc[j][f] = a;
            }
        }
    }

    float4 b0 = *(const float4*)&bl[tx * 8];
    float4 b1 = *(const float4*)&bl[tx * 8 + 4];
    const float bias[8] = {b0.x, b0.y, b0.z, b0.w, b1.x, b1.y, b1.z, b1.w};
#pragma unroll
    for (int j = 0; j < 4; ++j) {
        int node = nbase + j;
        if (node < N_NODES) {
            float o[8];
#pragma unroll
            for (int f = 0; f < 8; ++f) o[f] = fmaxf(acc[j][f] + bias[f], 0.0f);
            *(float4*)&x[node * H + tx * 8]     = make_float4(o[0], o[1], o[2], o[3]);
            *(float4*)&x[node * H + tx * 8 + 4] = make_float4(o[4], o[5], o[6], o[7]);
            if (writeBf) {
                uint4 p;
                p.x = (unsigned)f2bf(o[0]) | ((unsigned)f2bf(o[1]) << 16);
                p.y = (unsigned)f2bf(o[2]) | ((unsigned)f2bf(o[3]) << 16);
                p.z = (unsigned)f2bf(o[4]) | ((unsigned)f2bf(o[5]) << 16);
                p.w = (unsigned)f2bf(o[6]) | ((unsigned)f2bf(o[7]) << 16);
                *(uint4*)&xh[node * H + tx * 8] = p;
            }
        }
    }
}

// ---------------------------------------------------------------------------
// Final MLP: rating = clip(relu(pair @ W1 + b1) @ W2 + b2, 1, 5)
__global__ __launch_bounds__(256) void mlp_kernel(const float* __restrict__ x,
                                                  const int* __restrict__ uids,
                                                  const int* __restrict__ iids,
                                                  const float* __restrict__ W1,
                                                  const float* __restrict__ b1,
                                                  const float* __restrict__ W2,
                                                  const float* __restrict__ b2,
                                                  float* __restrict__ out) {
    __shared__ float sW1[2 * H * MLP_HIDDEN];
    __shared__ float sPair[8][2 * H];
    __shared__ float sW2[MLP_HIDDEN];

    for (int i = threadIdx.x; i < 2 * H * MLP_HIDDEN; i += 256) sW1[i] = W1[i];
    if (threadIdx.x < MLP_HIDDEN) sW2[threadIdx.x] = W2[threadIdx.x];

    int slot = threadIdx.x >> 5;
    int j    = threadIdx.x & 31;
    int b = blockIdx.x * 8 + slot;                 // BATCH % 8 == 0

    int u  = uids[b];
    int it = iids[b] + NUM_USERS;
    float2 a = *(const float2*)&x[u * H + j * 2];
    sPair[slot][j * 2]     = a.x;
    sPair[slot][j * 2 + 1] = a.y;
    float2 c = *(const float2*)&x[it * H + j * 2];
    sPair[slot][H + j * 2]     = c.x;
    sPair[slot][H + j * 2 + 1] = c.y;
    __syncthreads();

    float hacc = b1[j];
#pragma unroll
    for (int k = 0; k < 2 * H; ++k)
        hacc = fmaf(sPair[slot][k], sW1[k * MLP_HIDDEN + j], hacc);
    hacc = fmaxf(hacc, 0.0f);

    float r = hacc * sW2[j];
#pragma unroll
    for (int off = 16; off; off >>= 1) r += __shfl_down(r, off, 32);

    if (j == 0) out[b] = fminf(fmaxf(r + b2[0], 1.0f), 5.0f);
}

// ---------------------------------------------------------------------------
extern "C" void kernel_launch(void* const* d_in, const int* in_sizes, int n_in,
                              void* d_out, int out_size, void* d_ws, size_t ws_size,
                              hipStream_t stream) {
    const int*   edge_index = (const int*)d_in[0];
    const int*   user_ids   = (const int*)d_in[1];
    const int*   item_ids   = (const int*)d_in[2];
    const float* user_emb   = (const float*)d_in[3];
    const float* item_emb   = (const float*)d_in[4];
    const float* Wl         = (const float*)d_in[5];
    const float* bl         = (const float*)d_in[6];
    const float* Wr         = (const float*)d_in[7];
    const float* W1         = (const float*)d_in[8];
    const float* b1         = (const float*)d_in[9];
    const float* W2         = (const float*)d_in[10];
    const float* b2         = (const float*)d_in[11];
    float* out = (float*)d_out;

    const int* src = edge_index;
    const int* dst = edge_index + N_EDGES;

    const size_t NH = (size_t)N_NODES * H;
    float* x          = (float*)d_ws;                    // 38.4 MB fp32
    // ebuf region (19.2 MB) doubles as mean_bf after CSR build is done
    int* ebuf         = (int*)(x + NH);                  // NBUCK*BCAP*4 B
    ushort_t* mean_bf = (ushort_t*)ebuf;                 // bf16 overlay
    ushort_t* xh      = (ushort_t*)(ebuf + (size_t)NBUCK * BCAP);  // 19.2 MB bf16
    int* deg          = (int*)(xh + NH);                 // 600 KB
    int* offsets      = deg + N_NODES;                   // 600 KB
    int* bucketCnt    = offsets + N_NODES;               // 2.3 KB
    int* csr          = bucketCnt + NBUCK;               // 19.2 MB (BCAP-strided)

    init_kernel<<<(N_NODES * H / 4) / 256, 256, 0, stream>>>(user_emb, item_emb, x, xh);

    // CSR build: fixed-capacity counting sort (graph identical across layers)
    hipMemsetAsync(bucketCnt, 0, NBUCK * sizeof(int), stream);
    bucket_scatter_kernel<<<(N_EDGES + SCHUNK - 1) / SCHUNK, 256, 0, stream>>>(
        src, dst, bucketCnt, ebuf);
    bucket_build_kernel<<<NBUCK, 256, 0, stream>>>(ebuf, bucketCnt, deg, offsets, csr);

    const int TGRID = (N_NODES + 127) / 128;             // 1172
    for (int l = 0; l < 3; ++l) {
        gather_mean_kernel<<<N_NODES / 4, 256, 0, stream>>>(xh, mean_bf, offsets, deg, csr);
        transform_kernel<<<TGRID, 256, 0, stream>>>(
            x, xh, mean_bf, Wl + (size_t)l * H * H, bl + (size_t)l * H,
            Wr + (size_t)l * H * H, l < 2 ? 1 : 0);
    }

    mlp_kernel<<<BATCH / 8, 256, 0, stream>>>(x, user_ids, item_ids, W1, b1, W2, b2, out);
}